// Round 1
// baseline (2103.499 us; speedup 1.0000x reference)
//
#include <hip/hip_runtime.h>

// GAT layer: N nodes, E edges, IN=128 -> H*C=128, H=4 heads, C=32.
// Pipeline:
//   k_init : out = bias, menc = enc(-inf-ish), denom = 0
//   k_gemm : h = x@W (W cached in LDS, 64KB), fused alpha_src/alpha_dst
//   k_max  : segment-max of leaky_relu logits per (dst, head) via atomicMax on encoded uint
//   k_denom: segment-sum of exp(logit - max) per (dst, head)
//   k_agg  : wave-per-edge weighted scatter of h[src] into out[dst] via f32 atomics

__device__ __forceinline__ unsigned fenc(float f) {
  unsigned u = __float_as_uint(f);
  return (u & 0x80000000u) ? ~u : (u | 0x80000000u);
}
__device__ __forceinline__ float fdec(unsigned u) {
  return (u & 0x80000000u) ? __uint_as_float(u ^ 0x80000000u) : __uint_as_float(~u);
}
__device__ __forceinline__ float lrelu(float x) { return x >= 0.f ? x : 0.2f * x; }

__global__ __launch_bounds__(256) void k_init(float* __restrict__ out, const float* __restrict__ bias,
                                              unsigned* __restrict__ menc, float* __restrict__ denom, int n) {
  int i = blockIdx.x * 256 + threadIdx.x;
  if (i < n * 128) out[i] = bias[i & 127];
  if (i < n * 4) { menc[i] = 0u; denom[i] = 0.f; }
}

__global__ __launch_bounds__(256) void k_gemm(const float* __restrict__ x, const float* __restrict__ W,
                                              const float* __restrict__ a_src, const float* __restrict__ a_dst,
                                              float* __restrict__ h, float* __restrict__ asrc,
                                              float* __restrict__ adst, int n) {
  __shared__ float Wl[128 * 128];   // 64 KB: whole weight matrix
  __shared__ float xs[8][128];      // 8 staged x rows
  int t = threadIdx.x;
  {
    const float4* W4 = (const float4*)W;
    float4* Wl4 = (float4*)Wl;
    for (int i = t; i < 128 * 128 / 4; i += 256) Wl4[i] = W4[i];
  }
  int cg = t & 31;        // column group: cols [4*cg, 4*cg+3]
  int head = cg >> 3;     // 4 consecutive cols stay within one head (32 cols/head)
  float4 as4 = ((const float4*)a_src)[cg];
  float4 ad4 = ((const float4*)a_dst)[cg];
  int rr = t >> 5;        // 0..7: row within staged chunk
  int rbase = blockIdx.x * 64;
  for (int chunk = 0; chunk < 64; chunk += 8) {
    __syncthreads();
    int row = rbase + chunk + rr;
    float4 v = make_float4(0.f, 0.f, 0.f, 0.f);
    if (row < n) v = ((const float4*)(x + (size_t)row * 128))[cg];
    ((float4*)&xs[rr][0])[cg] = v;
    __syncthreads();
    float a0 = 0.f, a1 = 0.f, a2 = 0.f, a3 = 0.f;
#pragma unroll 4
    for (int k = 0; k < 128; ++k) {
      float xv = xs[rr][k];
      float4 w = ((const float4*)(Wl + k * 128))[cg];
      a0 += xv * w.x; a1 += xv * w.y; a2 += xv * w.z; a3 += xv * w.w;
    }
    if (row < n) {
      ((float4*)(h + (size_t)row * 128))[cg] = make_float4(a0, a1, a2, a3);
      float ps = a0 * as4.x + a1 * as4.y + a2 * as4.z + a3 * as4.w;
      float pd = a0 * ad4.x + a1 * ad4.y + a2 * ad4.z + a3 * ad4.w;
#pragma unroll
      for (int m = 1; m < 8; m <<= 1) {
        ps += __shfl_xor(ps, m, 64);
        pd += __shfl_xor(pd, m, 64);
      }
      if ((cg & 7) == 0) {
        asrc[row * 4 + head] = ps;
        adst[row * 4 + head] = pd;
      }
    }
  }
}

__global__ __launch_bounds__(256) void k_max(const int* __restrict__ ei, const float* __restrict__ asrc,
                                             const float* __restrict__ adst, unsigned* __restrict__ menc,
                                             int n, int e) {
  int i = blockIdx.x * 256 + threadIdx.x;
  if (i >= e + n) return;
  int s, d;
  if (i < e) { s = ei[i]; d = ei[e + i]; } else { s = d = i - e; }
  float4 av = ((const float4*)asrc)[s];
  float4 bv = ((const float4*)adst)[d];
  atomicMax(&menc[d * 4 + 0], fenc(lrelu(av.x + bv.x)));
  atomicMax(&menc[d * 4 + 1], fenc(lrelu(av.y + bv.y)));
  atomicMax(&menc[d * 4 + 2], fenc(lrelu(av.z + bv.z)));
  atomicMax(&menc[d * 4 + 3], fenc(lrelu(av.w + bv.w)));
}

__global__ __launch_bounds__(256) void k_denom(const int* __restrict__ ei, const float* __restrict__ asrc,
                                               const float* __restrict__ adst, const unsigned* __restrict__ menc,
                                               float* __restrict__ denom, int n, int e) {
  int i = blockIdx.x * 256 + threadIdx.x;
  if (i >= e + n) return;
  int s, d;
  if (i < e) { s = ei[i]; d = ei[e + i]; } else { s = d = i - e; }
  float4 av = ((const float4*)asrc)[s];
  float4 bv = ((const float4*)adst)[d];
  atomicAdd(&denom[d * 4 + 0], __expf(lrelu(av.x + bv.x) - fdec(menc[d * 4 + 0])));
  atomicAdd(&denom[d * 4 + 1], __expf(lrelu(av.y + bv.y) - fdec(menc[d * 4 + 1])));
  atomicAdd(&denom[d * 4 + 2], __expf(lrelu(av.z + bv.z) - fdec(menc[d * 4 + 2])));
  atomicAdd(&denom[d * 4 + 3], __expf(lrelu(av.w + bv.w) - fdec(menc[d * 4 + 3])));
}

__global__ __launch_bounds__(256) void k_agg(const int* __restrict__ ei, const float* __restrict__ asrc,
                                             const float* __restrict__ adst, const unsigned* __restrict__ menc,
                                             const float* __restrict__ denom, const float* __restrict__ h,
                                             float* __restrict__ out, int n, int e) {
  int gid = blockIdx.x * 256 + threadIdx.x;
  int wid = gid >> 6;   // one wave per edge
  int lane = gid & 63;  // lane handles channels [2*lane, 2*lane+1]
  if (wid >= e + n) return;
  int s, d;
  if (wid < e) { s = ei[wid]; d = ei[e + wid]; } else { s = d = wid - e; }
  int head = lane >> 4;
  float la = lrelu(asrc[s * 4 + head] + adst[d * 4 + head]);
  float w = __expf(la - fdec(menc[d * 4 + head])) / denom[d * 4 + head];
  float2 hv = ((const float2*)(h + (size_t)s * 128))[lane];
  atomicAdd(&out[(size_t)d * 128 + lane * 2 + 0], w * hv.x);
  atomicAdd(&out[(size_t)d * 128 + lane * 2 + 1], w * hv.y);
}

extern "C" void kernel_launch(void* const* d_in, const int* in_sizes, int n_in,
                              void* d_out, int out_size, void* d_ws, size_t ws_size,
                              hipStream_t stream) {
  const float* x     = (const float*)d_in[0];
  const int*   ei    = (const int*)d_in[1];
  const float* W     = (const float*)d_in[2];
  const float* a_src = (const float*)d_in[3];
  const float* a_dst = (const float*)d_in[4];
  const float* bias  = (const float*)d_in[5];
  float* out = (float*)d_out;

  int n = in_sizes[0] / 128;   // IN = 128
  int e = in_sizes[1] / 2;
  int tot = e + n;

  char* ws = (char*)d_ws;
  size_t off = 0;
  float* h = (float*)(ws + off);      off += (size_t)n * 128 * sizeof(float);   // 51.2 MB
  float* asrc = (float*)(ws + off);   off += (size_t)n * 4 * sizeof(float);
  float* adst = (float*)(ws + off);   off += (size_t)n * 4 * sizeof(float);
  unsigned* menc = (unsigned*)(ws + off); off += (size_t)n * 4 * sizeof(unsigned);
  float* denom = (float*)(ws + off);  off += (size_t)n * 4 * sizeof(float);

  hipLaunchKernelGGL(k_init, dim3((n * 128 + 255) / 256), dim3(256), 0, stream,
                     out, bias, menc, denom, n);
  hipLaunchKernelGGL(k_gemm, dim3((n + 63) / 64), dim3(256), 0, stream,
                     x, W, a_src, a_dst, h, asrc, adst, n);
  hipLaunchKernelGGL(k_max, dim3((tot + 255) / 256), dim3(256), 0, stream,
                     ei, asrc, adst, menc, n, e);
  hipLaunchKernelGGL(k_denom, dim3((tot + 255) / 256), dim3(256), 0, stream,
                     ei, asrc, adst, menc, denom, n, e);
  hipLaunchKernelGGL(k_agg, dim3((tot + 3) / 4), dim3(256), 0, stream,
                     ei, asrc, adst, menc, denom, h, out, n, e);
}

// Round 2
// 495.180 us; speedup vs baseline: 4.2479x; 4.2479x over previous
//
#include <hip/hip_runtime.h>

// GAT layer: N nodes, E edges, IN=128 -> H*C=128, H=4 heads, C=32.
// Pipeline (no output atomics):
//   k_init  : zero degree counters, off[n]=e
//   k_gemm  : h = x@W (W cached in LDS, 64KB), fused alpha_src/alpha_dst
//   k_count : per-edge dst degree histogram (int atomics, L2-resident)
//   k_scan1/2/3 : exclusive scan of degrees -> CSR offsets (also re-zeros cnt as cursor)
//   k_fill  : scatter src ids into dst-CSR adjacency (cursor atomics)
//   k_reduce: one wave per dst node, online-softmax reduce over incoming edges,
//             h gather served by L3, single coalesced out write.

__device__ __forceinline__ float lrelu(float x) { return x >= 0.f ? x : 0.2f * x; }

__global__ __launch_bounds__(256) void k_init(int* __restrict__ cnt, int* __restrict__ off, int n, int e) {
  int i = blockIdx.x * 256 + threadIdx.x;
  if (i < n) cnt[i] = 0;
  if (i == 0) off[n] = e;
}

__global__ __launch_bounds__(256) void k_gemm(const float* __restrict__ x, const float* __restrict__ W,
                                              const float* __restrict__ a_src, const float* __restrict__ a_dst,
                                              float* __restrict__ h, float* __restrict__ asrc,
                                              float* __restrict__ adst, int n) {
  __shared__ float Wl[128 * 128];   // 64 KB: whole weight matrix
  __shared__ float xs[8][128];      // 8 staged x rows
  int t = threadIdx.x;
  {
    const float4* W4 = (const float4*)W;
    float4* Wl4 = (float4*)Wl;
    for (int i = t; i < 128 * 128 / 4; i += 256) Wl4[i] = W4[i];
  }
  int cg = t & 31;        // column group: cols [4*cg, 4*cg+3]
  int head = cg >> 3;     // 4 consecutive cols stay within one head (32 cols/head)
  float4 as4 = ((const float4*)a_src)[cg];
  float4 ad4 = ((const float4*)a_dst)[cg];
  int rr = t >> 5;        // 0..7: row within staged chunk
  int rbase = blockIdx.x * 64;
  for (int chunk = 0; chunk < 64; chunk += 8) {
    __syncthreads();
    int row = rbase + chunk + rr;
    float4 v = make_float4(0.f, 0.f, 0.f, 0.f);
    if (row < n) v = ((const float4*)(x + (size_t)row * 128))[cg];
    ((float4*)&xs[rr][0])[cg] = v;
    __syncthreads();
    float a0 = 0.f, a1 = 0.f, a2 = 0.f, a3 = 0.f;
#pragma unroll 4
    for (int k = 0; k < 128; ++k) {
      float xv = xs[rr][k];
      float4 w = ((const float4*)(Wl + k * 128))[cg];
      a0 += xv * w.x; a1 += xv * w.y; a2 += xv * w.z; a3 += xv * w.w;
    }
    if (row < n) {
      ((float4*)(h + (size_t)row * 128))[cg] = make_float4(a0, a1, a2, a3);
      float ps = a0 * as4.x + a1 * as4.y + a2 * as4.z + a3 * as4.w;
      float pd = a0 * ad4.x + a1 * ad4.y + a2 * ad4.z + a3 * ad4.w;
#pragma unroll
      for (int m = 1; m < 8; m <<= 1) {
        ps += __shfl_xor(ps, m, 64);
        pd += __shfl_xor(pd, m, 64);
      }
      if ((cg & 7) == 0) {
        asrc[row * 4 + head] = ps;
        adst[row * 4 + head] = pd;
      }
    }
  }
}

__global__ __launch_bounds__(256) void k_count(const int* __restrict__ ei, int* __restrict__ cnt, int e) {
  int i = blockIdx.x * 256 + threadIdx.x;
  if (i < e) atomicAdd(&cnt[ei[e + i]], 1);
}

__global__ __launch_bounds__(256) void k_scan1(const int* __restrict__ cnt, int* __restrict__ off,
                                               int* __restrict__ bsum, int n) {
  __shared__ int s[256];
  int b = blockIdx.x, t = threadIdx.x, i = b * 256 + t;
  int v = (i < n) ? cnt[i] : 0;
  s[t] = v; __syncthreads();
  for (int ofs = 1; ofs < 256; ofs <<= 1) {
    int u = (t >= ofs) ? s[t - ofs] : 0; __syncthreads();
    s[t] += u; __syncthreads();
  }
  if (i < n) off[i] = s[t] - v;          // chunk-exclusive
  if (t == 255) bsum[b] = s[255];
}

__global__ __launch_bounds__(256) void k_scan2(const int* __restrict__ bsum, int* __restrict__ bscan, int nb) {
  __shared__ int s[256];
  int t = threadIdx.x;
  int carry = 0;
  for (int c = 0; c < nb; c += 256) {
    int i = c + t;
    int v = (i < nb) ? bsum[i] : 0;
    s[t] = v; __syncthreads();
    for (int ofs = 1; ofs < 256; ofs <<= 1) {
      int u = (t >= ofs) ? s[t - ofs] : 0; __syncthreads();
      s[t] += u; __syncthreads();
    }
    if (i < nb) bscan[i] = carry + s[t] - v;
    carry += s[255];
    __syncthreads();
  }
}

__global__ __launch_bounds__(256) void k_scan3(int* __restrict__ off, const int* __restrict__ bscan,
                                               int* __restrict__ cnt, int n) {
  int i = blockIdx.x * 256 + threadIdx.x;
  if (i < n) { off[i] += bscan[i >> 8]; cnt[i] = 0; }   // cnt becomes fill cursor
}

__global__ __launch_bounds__(256) void k_fill(const int* __restrict__ ei, const int* __restrict__ off,
                                              int* __restrict__ cnt, int* __restrict__ adj, int e) {
  int i = blockIdx.x * 256 + threadIdx.x;
  if (i >= e) return;
  int s = ei[i], d = ei[e + i];
  int pos = atomicAdd(&cnt[d], 1);
  adj[off[d] + pos] = s;
}

__global__ __launch_bounds__(256) void k_reduce(const int* __restrict__ adj, const int* __restrict__ off,
                                                const float* __restrict__ asrc, const float* __restrict__ adst,
                                                const float* __restrict__ h, const float* __restrict__ bias,
                                                float* __restrict__ out, int n) {
  int gid = blockIdx.x * 256 + threadIdx.x;
  int node = gid >> 6, lane = gid & 63;
  if (node >= n) return;
  int head = lane >> 4;
  float ad = adst[node * 4 + head];
  // self-loop seeds the online softmax: m = la_self, denom = 1, acc = h[node]
  float m = lrelu(asrc[node * 4 + head] + ad);
  float2 hv = ((const float2*)(h + (size_t)node * 128))[lane];
  float denom = 1.f;
  float acc0 = hv.x, acc1 = hv.y;
  int o = off[node], oend = off[node + 1];
  for (int j = o; j < oend; ++j) {
    int s = adj[j];
    float la = lrelu(asrc[s * 4 + head] + ad);
    float mn = fmaxf(m, la);
    float scale = __expf(m - mn);
    float p = __expf(la - mn);
    hv = ((const float2*)(h + (size_t)s * 128))[lane];
    denom = denom * scale + p;
    acc0 = acc0 * scale + p * hv.x;
    acc1 = acc1 * scale + p * hv.y;
    m = mn;
  }
  float inv = 1.f / denom;
  float2 b = ((const float2*)bias)[lane];
  ((float2*)(out + (size_t)node * 128))[lane] = make_float2(acc0 * inv + b.x, acc1 * inv + b.y);
}

extern "C" void kernel_launch(void* const* d_in, const int* in_sizes, int n_in,
                              void* d_out, int out_size, void* d_ws, size_t ws_size,
                              hipStream_t stream) {
  const float* x     = (const float*)d_in[0];
  const int*   ei    = (const int*)d_in[1];
  const float* W     = (const float*)d_in[2];
  const float* a_src = (const float*)d_in[3];
  const float* a_dst = (const float*)d_in[4];
  const float* bias  = (const float*)d_in[5];
  float* out = (float*)d_out;

  int n = in_sizes[0] / 128;   // IN = 128
  int e = in_sizes[1] / 2;
  int nb = (n + 255) / 256;

  char* ws = (char*)d_ws;
  size_t off_b = 0;
  float* h    = (float*)(ws + off_b); off_b += (size_t)n * 128 * sizeof(float);  // 51.2 MB
  float* asrc = (float*)(ws + off_b); off_b += (size_t)n * 4 * sizeof(float);
  float* adst = (float*)(ws + off_b); off_b += (size_t)n * 4 * sizeof(float);
  int* cnt    = (int*)(ws + off_b);   off_b += (size_t)n * sizeof(int);
  int* off    = (int*)(ws + off_b);   off_b += (size_t)(n + 1) * sizeof(int);
  int* bsum   = (int*)(ws + off_b);   off_b += (size_t)nb * sizeof(int);
  int* bscan  = (int*)(ws + off_b);   off_b += (size_t)nb * sizeof(int);
  int* adj    = (int*)(ws + off_b);   off_b += (size_t)e * sizeof(int);          // 6.4 MB

  hipLaunchKernelGGL(k_init, dim3((n + 255) / 256), dim3(256), 0, stream, cnt, off, n, e);
  hipLaunchKernelGGL(k_gemm, dim3((n + 63) / 64), dim3(256), 0, stream,
                     x, W, a_src, a_dst, h, asrc, adst, n);
  hipLaunchKernelGGL(k_count, dim3((e + 255) / 256), dim3(256), 0, stream, ei, cnt, e);
  hipLaunchKernelGGL(k_scan1, dim3(nb), dim3(256), 0, stream, cnt, off, bsum, n);
  hipLaunchKernelGGL(k_scan2, dim3(1), dim3(256), 0, stream, bsum, bscan, nb);
  hipLaunchKernelGGL(k_scan3, dim3(nb), dim3(256), 0, stream, off, bscan, cnt, n);
  hipLaunchKernelGGL(k_fill, dim3((e + 255) / 256), dim3(256), 0, stream, ei, off, cnt, adj, e);
  hipLaunchKernelGGL(k_reduce, dim3((n * 64 + 255) / 256), dim3(256), 0, stream,
                     adj, off, asrc, adst, h, bias, out, n);
}

// Round 3
// 308.343 us; speedup vs baseline: 6.8219x; 1.6059x over previous
//
#include <hip/hip_runtime.h>
#include <stdint.h>

// GAT layer: N nodes, E edges, IN=128 -> H*C=128, H=4 heads, C=32.
// Pipeline:
//   k_init  : zero degree counters, off[n]=e
//   k_wprep : Wt[n][k] = bf16(W[k][n])  (transpose+convert, 16K elems)
//   k_gemm  : h(bf16) = bf16(x) @ Wt via mfma_f32_16x16x32_bf16, Wt in swizzled LDS
//   k_alpha : asrc/adst per (node,head) from h (wave-per-row dot products)
//   k_count/k_scan1,2,3/k_fill : dst-CSR build
//   k_reduce: wave-per-dst-node online-softmax reduce, 4-way unrolled gathers (bf16 h)

typedef __bf16 bf16x8 __attribute__((ext_vector_type(8)));
typedef float f32x4 __attribute__((ext_vector_type(4)));

__device__ __forceinline__ float lrelu(float x) { return x >= 0.f ? x : 0.2f * x; }
__device__ __forceinline__ float blo(unsigned u) { return __uint_as_float(u << 16); }
__device__ __forceinline__ float bhi(unsigned u) { return __uint_as_float(u & 0xffff0000u); }

__global__ __launch_bounds__(256) void k_init(int* __restrict__ cnt, int* __restrict__ off, int n, int e) {
  int i = blockIdx.x * 256 + threadIdx.x;
  if (i < n) cnt[i] = 0;
  if (i == 0) off[n] = e;
}

__global__ __launch_bounds__(256) void k_wprep(const float* __restrict__ W, __bf16* __restrict__ Wt) {
  int idx = blockIdx.x * 256 + threadIdx.x;   // grid = 64 blocks covers 128*128
  int nn = idx & 127, k = idx >> 7;
  Wt[nn * 128 + k] = (__bf16)W[k * 128 + nn];
}

#define CPB 2   // row-chunks of 64 per block
__global__ __launch_bounds__(256) void k_gemm(const float* __restrict__ x, const __bf16* __restrict__ Wt,
                                              __bf16* __restrict__ h, int n) {
  __shared__ __align__(16) char Wl[32768];   // Wt[n][k] bf16, XOR-swizzled
  int t = threadIdx.x;
  {
    const float4* s4 = (const float4*)Wt;
    for (int i = t; i < 2048; i += 256) {
      int f = i << 4;
      int nr = f >> 8, c = f & 255;
      *(float4*)(Wl + ((nr << 8) | (c ^ ((nr & 7) << 4)))) = s4[i];
    }
  }
  __syncthreads();
  int wv = t >> 6, lane = t & 63;
  int arow = lane & 15, ag = lane >> 4, c15 = lane & 15;
  for (int cidx = 0; cidx < CPB; ++cidx) {
    int strip = (blockIdx.x * CPB + cidx) * 64 + wv * 16;
    int row = strip + arow;
    float4 fa[8];
    if (row < n) {
      const float4* xr = (const float4*)(x + (size_t)row * 128);
#pragma unroll
      for (int q = 0; q < 4; ++q) {
        fa[2 * q]     = xr[q * 8 + ag * 2];
        fa[2 * q + 1] = xr[q * 8 + ag * 2 + 1];
      }
    } else {
#pragma unroll
      for (int q = 0; q < 8; ++q) fa[q] = make_float4(0.f, 0.f, 0.f, 0.f);
    }
    bf16x8 af[4];
#pragma unroll
    for (int q = 0; q < 4; ++q) {
      af[q][0] = (__bf16)fa[2 * q].x;     af[q][1] = (__bf16)fa[2 * q].y;
      af[q][2] = (__bf16)fa[2 * q].z;     af[q][3] = (__bf16)fa[2 * q].w;
      af[q][4] = (__bf16)fa[2 * q + 1].x; af[q][5] = (__bf16)fa[2 * q + 1].y;
      af[q][6] = (__bf16)fa[2 * q + 1].z; af[q][7] = (__bf16)fa[2 * q + 1].w;
    }
    f32x4 acc[8];
#pragma unroll
    for (int tile = 0; tile < 8; ++tile) acc[tile] = (f32x4){0.f, 0.f, 0.f, 0.f};
#pragma unroll
    for (int q = 0; q < 4; ++q) {        // K-steps outer -> 8 independent MFMA chains
      int gb = (q * 64) + (ag << 4);
#pragma unroll
      for (int tile = 0; tile < 8; ++tile) {
        int nn = tile * 16 + c15;
        bf16x8 bf = *(const bf16x8*)(Wl + ((nn << 8) | (gb ^ ((nn & 7) << 4))));
        acc[tile] = __builtin_amdgcn_mfma_f32_16x16x32_bf16(af[q], bf, acc[tile], 0, 0, 0);
      }
    }
    int rbase = strip + (lane >> 4) * 4;   // D: row=(lane>>4)*4+r, col=lane&15
#pragma unroll
    for (int tile = 0; tile < 8; ++tile) {
      int col = tile * 16 + c15;
#pragma unroll
      for (int r = 0; r < 4; ++r) {
        int ro = rbase + r;
        if (ro < n) h[(size_t)ro * 128 + col] = (__bf16)acc[tile][r];
      }
    }
  }
}

__global__ __launch_bounds__(256) void k_alpha(const unsigned* __restrict__ h32,
                                               const float* __restrict__ a_src, const float* __restrict__ a_dst,
                                               float* __restrict__ asrc, float* __restrict__ adst, int n) {
  int gid = blockIdx.x * 256 + threadIdx.x;
  int row = gid >> 6, lane = gid & 63;
  if (row >= n) return;
  unsigned u = h32[(size_t)row * 64 + lane];
  float lo = blo(u), hi = bhi(u);
  float2 as = ((const float2*)a_src)[lane];
  float2 ad = ((const float2*)a_dst)[lane];
  float ps = lo * as.x + hi * as.y;
  float pd = lo * ad.x + hi * ad.y;
#pragma unroll
  for (int m = 1; m < 16; m <<= 1) {
    ps += __shfl_xor(ps, m, 64);
    pd += __shfl_xor(pd, m, 64);
  }
  if ((lane & 15) == 0) {
    asrc[row * 4 + (lane >> 4)] = ps;
    adst[row * 4 + (lane >> 4)] = pd;
  }
}

__global__ __launch_bounds__(256) void k_count(const int* __restrict__ ei, int* __restrict__ cnt, int e) {
  int i = blockIdx.x * 256 + threadIdx.x;
  if (i < e) atomicAdd(&cnt[ei[e + i]], 1);
}

__global__ __launch_bounds__(256) void k_scan1(const int* __restrict__ cnt, int* __restrict__ off,
                                               int* __restrict__ bsum, int n) {
  __shared__ int s[256];
  int b = blockIdx.x, t = threadIdx.x, i = b * 256 + t;
  int v = (i < n) ? cnt[i] : 0;
  s[t] = v; __syncthreads();
  for (int ofs = 1; ofs < 256; ofs <<= 1) {
    int u = (t >= ofs) ? s[t - ofs] : 0; __syncthreads();
    s[t] += u; __syncthreads();
  }
  if (i < n) off[i] = s[t] - v;
  if (t == 255) bsum[b] = s[255];
}

__global__ __launch_bounds__(256) void k_scan2(const int* __restrict__ bsum, int* __restrict__ bscan, int nb) {
  __shared__ int s[256];
  int t = threadIdx.x;
  int carry = 0;
  for (int c = 0; c < nb; c += 256) {
    int i = c + t;
    int v = (i < nb) ? bsum[i] : 0;
    s[t] = v; __syncthreads();
    for (int ofs = 1; ofs < 256; ofs <<= 1) {
      int u = (t >= ofs) ? s[t - ofs] : 0; __syncthreads();
      s[t] += u; __syncthreads();
    }
    if (i < nb) bscan[i] = carry + s[t] - v;
    carry += s[255];
    __syncthreads();
  }
}

__global__ __launch_bounds__(256) void k_scan3(int* __restrict__ off, const int* __restrict__ bscan,
                                               int* __restrict__ cnt, int n) {
  int i = blockIdx.x * 256 + threadIdx.x;
  if (i < n) { off[i] += bscan[i >> 8]; cnt[i] = 0; }
}

__global__ __launch_bounds__(256) void k_fill(const int* __restrict__ ei, const int* __restrict__ off,
                                              int* __restrict__ cnt, int* __restrict__ adj, int e) {
  int i = blockIdx.x * 256 + threadIdx.x;
  if (i >= e) return;
  int s = ei[i], d = ei[e + i];
  int pos = atomicAdd(&cnt[d], 1);
  adj[off[d] + pos] = s;
}

__global__ __launch_bounds__(256) void k_reduce(const int* __restrict__ adj, const int* __restrict__ off,
                                                const float* __restrict__ asrc, const float* __restrict__ adst,
                                                const unsigned* __restrict__ h32, const float* __restrict__ bias,
                                                float* __restrict__ out, int n) {
  int gid = blockIdx.x * 256 + threadIdx.x;
  int node = gid >> 6, lane = gid & 63;
  if (node >= n) return;
  int head = lane >> 4;
  float ad = adst[node * 4 + head];
  float m = lrelu(asrc[node * 4 + head] + ad);   // self-loop seed
  unsigned su = h32[(size_t)node * 64 + lane];
  float denom = 1.f, acc0 = blo(su), acc1 = bhi(su);
  int j = off[node], oe = off[node + 1];
  for (; j + 4 <= oe; j += 4) {
    int s0 = adj[j], s1 = adj[j + 1], s2 = adj[j + 2], s3 = adj[j + 3];
    unsigned u0 = h32[(size_t)s0 * 64 + lane];
    unsigned u1 = h32[(size_t)s1 * 64 + lane];
    unsigned u2 = h32[(size_t)s2 * 64 + lane];
    unsigned u3 = h32[(size_t)s3 * 64 + lane];
    float la0 = lrelu(asrc[s0 * 4 + head] + ad);
    float la1 = lrelu(asrc[s1 * 4 + head] + ad);
    float la2 = lrelu(asrc[s2 * 4 + head] + ad);
    float la3 = lrelu(asrc[s3 * 4 + head] + ad);
    float mx = fmaxf(fmaxf(fmaxf(la0, la1), fmaxf(la2, la3)), m);
    float scale = __expf(m - mx);
    float p0 = __expf(la0 - mx), p1 = __expf(la1 - mx);
    float p2 = __expf(la2 - mx), p3 = __expf(la3 - mx);
    denom = denom * scale + ((p0 + p1) + (p2 + p3));
    acc0 = acc0 * scale + p0 * blo(u0) + p1 * blo(u1) + p2 * blo(u2) + p3 * blo(u3);
    acc1 = acc1 * scale + p0 * bhi(u0) + p1 * bhi(u1) + p2 * bhi(u2) + p3 * bhi(u3);
    m = mx;
  }
  for (; j < oe; ++j) {
    int s = adj[j];
    unsigned u = h32[(size_t)s * 64 + lane];
    float la = lrelu(asrc[s * 4 + head] + ad);
    float mx = fmaxf(m, la);
    float scale = __expf(m - mx), p = __expf(la - mx);
    denom = denom * scale + p;
    acc0 = acc0 * scale + p * blo(u);
    acc1 = acc1 * scale + p * bhi(u);
    m = mx;
  }
  float inv = 1.f / denom;
  float2 b = ((const float2*)bias)[lane];
  ((float2*)(out + (size_t)node * 128))[lane] = make_float2(acc0 * inv + b.x, acc1 * inv + b.y);
}

extern "C" void kernel_launch(void* const* d_in, const int* in_sizes, int n_in,
                              void* d_out, int out_size, void* d_ws, size_t ws_size,
                              hipStream_t stream) {
  const float* x     = (const float*)d_in[0];
  const int*   ei    = (const int*)d_in[1];
  const float* W     = (const float*)d_in[2];
  const float* a_src = (const float*)d_in[3];
  const float* a_dst = (const float*)d_in[4];
  const float* bias  = (const float*)d_in[5];
  float* out = (float*)d_out;

  int n = in_sizes[0] / 128;   // IN = 128
  int e = in_sizes[1] / 2;
  int nb = (n + 255) / 256;

  char* ws = (char*)d_ws;
  size_t ofs = 0;
  __bf16* h   = (__bf16*)(ws + ofs); ofs += (size_t)n * 128 * sizeof(__bf16);   // 25.6 MB
  unsigned* h32 = (unsigned*)h;
  float* asrc = (float*)(ws + ofs); ofs += (size_t)n * 4 * sizeof(float);
  float* adst = (float*)(ws + ofs); ofs += (size_t)n * 4 * sizeof(float);
  int* cnt    = (int*)(ws + ofs);   ofs += (size_t)n * sizeof(int);
  int* off    = (int*)(ws + ofs);   ofs += (size_t)(n + 1) * sizeof(int);
  int* bsum   = (int*)(ws + ofs);   ofs += (size_t)nb * sizeof(int);
  int* bscan  = (int*)(ws + ofs);   ofs += (size_t)nb * sizeof(int);
  int* adj    = (int*)(ws + ofs);   ofs += (size_t)e * sizeof(int);             // 6.4 MB
  __bf16* Wt  = (__bf16*)(ws + ofs); ofs += (size_t)128 * 128 * sizeof(__bf16); // 32 KB

  hipLaunchKernelGGL(k_init, dim3((n + 255) / 256), dim3(256), 0, stream, cnt, off, n, e);
  hipLaunchKernelGGL(k_wprep, dim3(64), dim3(256), 0, stream, W, Wt);
  hipLaunchKernelGGL(k_gemm, dim3((n + 64 * CPB - 1) / (64 * CPB)), dim3(256), 0, stream, x, Wt, h, n);
  hipLaunchKernelGGL(k_alpha, dim3((n * 64 + 255) / 256), dim3(256), 0, stream,
                     h32, a_src, a_dst, asrc, adst, n);
  hipLaunchKernelGGL(k_count, dim3((e + 255) / 256), dim3(256), 0, stream, ei, cnt, e);
  hipLaunchKernelGGL(k_scan1, dim3(nb), dim3(256), 0, stream, cnt, off, bsum, n);
  hipLaunchKernelGGL(k_scan2, dim3(1), dim3(256), 0, stream, bsum, bscan, nb);
  hipLaunchKernelGGL(k_scan3, dim3(nb), dim3(256), 0, stream, off, bscan, cnt, n);
  hipLaunchKernelGGL(k_fill, dim3((e + 255) / 256), dim3(256), 0, stream, ei, off, cnt, adj, e);
  hipLaunchKernelGGL(k_reduce, dim3((n * 64 + 255) / 256), dim3(256), 0, stream,
                     adj, off, asrc, adst, h32, bias, out, n);
}

// Round 4
// 266.293 us; speedup vs baseline: 7.8992x; 1.1579x over previous
//
#include <hip/hip_runtime.h>
#include <stdint.h>

// GAT layer: N nodes, E edges, IN=128 -> H*C=128, H=4 heads, C=32.
// Pipeline:
//   k_init  : zero (bucket,group) counters, off[n]=e
//   k_wprep : Wt[n][k] = bf16(W[k][n])
//   k_gemm  : h(bf16) = bf16(x) @ Wt via mfma_f32_16x16x32_bf16, Wt in swizzled LDS
//   k_alpha : asrc/adst per (node,head) from h
//   k_bcount/k_bscan/k_bfill/k_csr : bucketed dst-CSR build (locality-friendly scatter)
//   k_reduce: wave-per-dst-node online-softmax reduce, 4-way unrolled bf16 gathers

typedef __bf16 bf16x8 __attribute__((ext_vector_type(8)));
typedef float f32x4 __attribute__((ext_vector_type(4)));

__device__ __forceinline__ float lrelu(float x) { return x >= 0.f ? x : 0.2f * x; }
__device__ __forceinline__ float blo(unsigned u) { return __uint_as_float(u << 16); }
__device__ __forceinline__ float bhi(unsigned u) { return __uint_as_float(u & 0xffff0000u); }

__global__ __launch_bounds__(256) void k_init(int* __restrict__ bgcnt, int* __restrict__ off,
                                              int n, int e, int nb8) {
  int i = blockIdx.x * 256 + threadIdx.x;
  if (i < nb8) bgcnt[i] = 0;
  if (i == 0) off[n] = e;
}

__global__ __launch_bounds__(256) void k_wprep(const float* __restrict__ W, __bf16* __restrict__ Wt) {
  int idx = blockIdx.x * 256 + threadIdx.x;   // grid = 64 blocks covers 128*128
  int nn = idx & 127, k = idx >> 7;
  Wt[nn * 128 + k] = (__bf16)W[k * 128 + nn];
}

#define CPB 2   // row-chunks of 64 per block
__global__ __launch_bounds__(256) void k_gemm(const float* __restrict__ x, const __bf16* __restrict__ Wt,
                                              __bf16* __restrict__ h, int n) {
  __shared__ __align__(16) char Wl[32768];   // Wt[n][k] bf16, XOR-swizzled
  int t = threadIdx.x;
  {
    const float4* s4 = (const float4*)Wt;
    for (int i = t; i < 2048; i += 256) {
      int f = i << 4;
      int nr = f >> 8, c = f & 255;
      *(float4*)(Wl + ((nr << 8) | (c ^ ((nr & 7) << 4)))) = s4[i];
    }
  }
  __syncthreads();
  int wv = t >> 6, lane = t & 63;
  int arow = lane & 15, ag = lane >> 4, c15 = lane & 15;
  for (int cidx = 0; cidx < CPB; ++cidx) {
    int strip = (blockIdx.x * CPB + cidx) * 64 + wv * 16;
    int row = strip + arow;
    float4 fa[8];
    if (row < n) {
      const float4* xr = (const float4*)(x + (size_t)row * 128);
#pragma unroll
      for (int q = 0; q < 4; ++q) {
        fa[2 * q]     = xr[q * 8 + ag * 2];
        fa[2 * q + 1] = xr[q * 8 + ag * 2 + 1];
      }
    } else {
#pragma unroll
      for (int q = 0; q < 8; ++q) fa[q] = make_float4(0.f, 0.f, 0.f, 0.f);
    }
    bf16x8 af[4];
#pragma unroll
    for (int q = 0; q < 4; ++q) {
      af[q][0] = (__bf16)fa[2 * q].x;     af[q][1] = (__bf16)fa[2 * q].y;
      af[q][2] = (__bf16)fa[2 * q].z;     af[q][3] = (__bf16)fa[2 * q].w;
      af[q][4] = (__bf16)fa[2 * q + 1].x; af[q][5] = (__bf16)fa[2 * q + 1].y;
      af[q][6] = (__bf16)fa[2 * q + 1].z; af[q][7] = (__bf16)fa[2 * q + 1].w;
    }
    f32x4 acc[8];
#pragma unroll
    for (int tile = 0; tile < 8; ++tile) acc[tile] = (f32x4){0.f, 0.f, 0.f, 0.f};
#pragma unroll
    for (int q = 0; q < 4; ++q) {
      int gb = (q * 64) + (ag << 4);
#pragma unroll
      for (int tile = 0; tile < 8; ++tile) {
        int nn = tile * 16 + c15;
        bf16x8 bf = *(const bf16x8*)(Wl + ((nn << 8) | (gb ^ ((nn & 7) << 4))));
        acc[tile] = __builtin_amdgcn_mfma_f32_16x16x32_bf16(af[q], bf, acc[tile], 0, 0, 0);
      }
    }
    int rbase = strip + (lane >> 4) * 4;   // D: row=(lane>>4)*4+r, col=lane&15
#pragma unroll
    for (int tile = 0; tile < 8; ++tile) {
      int col = tile * 16 + c15;
#pragma unroll
      for (int r = 0; r < 4; ++r) {
        int ro = rbase + r;
        if (ro < n) h[(size_t)ro * 128 + col] = (__bf16)acc[tile][r];
      }
    }
  }
}

__global__ __launch_bounds__(256) void k_alpha(const unsigned* __restrict__ h32,
                                               const float* __restrict__ a_src, const float* __restrict__ a_dst,
                                               float* __restrict__ asrc, float* __restrict__ adst, int n) {
  int gid = blockIdx.x * 256 + threadIdx.x;
  int row = gid >> 6, lane = gid & 63;
  if (row >= n) return;
  unsigned u = h32[(size_t)row * 64 + lane];
  float lo = blo(u), hi = bhi(u);
  float2 as = ((const float2*)a_src)[lane];
  float2 ad = ((const float2*)a_dst)[lane];
  float ps = lo * as.x + hi * as.y;
  float pd = lo * ad.x + hi * ad.y;
#pragma unroll
  for (int m = 1; m < 16; m <<= 1) {
    ps += __shfl_xor(ps, m, 64);
    pd += __shfl_xor(pd, m, 64);
  }
  if ((lane & 15) == 0) {
    asrc[row * 4 + (lane >> 4)] = ps;
    adst[row * 4 + (lane >> 4)] = pd;
  }
}

// --- bucketed CSR build: bucket = dst >> 7 (128 nodes), 8 block-groups ---

__global__ __launch_bounds__(256) void k_bcount(const int* __restrict__ ei, int* __restrict__ bgcnt,
                                                int e, int NB) {
  __shared__ int hist[1024];
  int t = threadIdx.x;
  for (int j = t; j < NB; j += 256) hist[j] = 0;
  __syncthreads();
  int step = gridDim.x * 256;
  for (int i = blockIdx.x * 256 + t; i < e; i += step)
    atomicAdd(&hist[ei[e + i] >> 7], 1);
  __syncthreads();
  int g = blockIdx.x & 7;
  for (int j = t; j < NB; j += 256) {
    int v = hist[j];
    if (v) atomicAdd(&bgcnt[j * 8 + g], v);
  }
}

__global__ __launch_bounds__(256) void k_bscan(const int* __restrict__ bgcnt, int* __restrict__ boffbg,
                                               int* __restrict__ bcur, int m, int e) {
  __shared__ int s[256];
  int t = threadIdx.x;
  int carry = 0;
  for (int c = 0; c < m; c += 256) {
    int i = c + t;
    int v = (i < m) ? bgcnt[i] : 0;
    s[t] = v; __syncthreads();
    for (int ofs = 1; ofs < 256; ofs <<= 1) {
      int u = (t >= ofs) ? s[t - ofs] : 0; __syncthreads();
      s[t] += u; __syncthreads();
    }
    if (i < m) { int ex = carry + s[t] - v; boffbg[i] = ex; bcur[i] = ex; }
    carry += s[255];
    __syncthreads();
  }
  if (t == 0) boffbg[m] = e;
}

__global__ __launch_bounds__(256) void k_bfill(const int* __restrict__ ei, int* __restrict__ bcur,
                                               unsigned* __restrict__ ebuf, int e) {
  int t = threadIdx.x, g = blockIdx.x & 7;
  int step = gridDim.x * 256;
  for (int i = blockIdx.x * 256 + t; i < e; i += step) {
    int s = ei[i], d = ei[e + i];
    int pos = atomicAdd(&bcur[(d >> 7) * 8 + g], 1);
    ebuf[pos] = ((unsigned)(d & 127) << 25) | (unsigned)s;
  }
}

__global__ __launch_bounds__(256) void k_csr(const unsigned* __restrict__ ebuf, const int* __restrict__ boffbg,
                                             int* __restrict__ off, int* __restrict__ adj, int n) {
  __shared__ int lcnt[128], lsc[128], lcur[128];
  int b = blockIdx.x, t = threadIdx.x;
  int s0 = boffbg[b * 8], s1 = boffbg[b * 8 + 8];
  if (t < 128) lcnt[t] = 0;
  __syncthreads();
  for (int j = s0 + t; j < s1; j += 256) atomicAdd(&lcnt[ebuf[j] >> 25], 1);
  __syncthreads();
  if (t < 128) lsc[t] = lcnt[t];
  __syncthreads();
  for (int ofs = 1; ofs < 128; ofs <<= 1) {
    int u = (t < 128 && t >= ofs) ? lsc[t - ofs] : 0;
    __syncthreads();
    if (t < 128) lsc[t] += u;
    __syncthreads();
  }
  int d0 = b << 7;
  if (t < 128) {
    int ex = lsc[t] - lcnt[t];
    lcur[t] = ex;
    if (d0 + t < n) off[d0 + t] = s0 + ex;
  }
  __syncthreads();
  for (int j = s0 + t; j < s1; j += 256) {
    unsigned u = ebuf[j];
    int pos = atomicAdd(&lcur[u >> 25], 1);
    adj[s0 + pos] = (int)(u & 0x1FFFFFFu);
  }
}

__global__ __launch_bounds__(256) void k_reduce(const int* __restrict__ adj, const int* __restrict__ off,
                                                const float* __restrict__ asrc, const float* __restrict__ adst,
                                                const unsigned* __restrict__ h32, const float* __restrict__ bias,
                                                float* __restrict__ out, int n) {
  int gid = blockIdx.x * 256 + threadIdx.x;
  int node = gid >> 6, lane = gid & 63;
  if (node >= n) return;
  int head = lane >> 4;
  float ad = adst[node * 4 + head];
  float m = lrelu(asrc[node * 4 + head] + ad);   // self-loop seed
  unsigned su = h32[(size_t)node * 64 + lane];
  float denom = 1.f, acc0 = blo(su), acc1 = bhi(su);
  int j = off[node], oe = off[node + 1];
  for (; j + 4 <= oe; j += 4) {
    int s0 = adj[j], s1 = adj[j + 1], s2 = adj[j + 2], s3 = adj[j + 3];
    unsigned u0 = h32[(size_t)s0 * 64 + lane];
    unsigned u1 = h32[(size_t)s1 * 64 + lane];
    unsigned u2 = h32[(size_t)s2 * 64 + lane];
    unsigned u3 = h32[(size_t)s3 * 64 + lane];
    float la0 = lrelu(asrc[s0 * 4 + head] + ad);
    float la1 = lrelu(asrc[s1 * 4 + head] + ad);
    float la2 = lrelu(asrc[s2 * 4 + head] + ad);
    float la3 = lrelu(asrc[s3 * 4 + head] + ad);
    float mx = fmaxf(fmaxf(fmaxf(la0, la1), fmaxf(la2, la3)), m);
    float scale = __expf(m - mx);
    float p0 = __expf(la0 - mx), p1 = __expf(la1 - mx);
    float p2 = __expf(la2 - mx), p3 = __expf(la3 - mx);
    denom = denom * scale + ((p0 + p1) + (p2 + p3));
    acc0 = acc0 * scale + p0 * blo(u0) + p1 * blo(u1) + p2 * blo(u2) + p3 * blo(u3);
    acc1 = acc1 * scale + p0 * bhi(u0) + p1 * bhi(u1) + p2 * bhi(u2) + p3 * bhi(u3);
    m = mx;
  }
  for (; j < oe; ++j) {
    int s = adj[j];
    unsigned u = h32[(size_t)s * 64 + lane];
    float la = lrelu(asrc[s * 4 + head] + ad);
    float mx = fmaxf(m, la);
    float scale = __expf(m - mx), p = __expf(la - mx);
    denom = denom * scale + p;
    acc0 = acc0 * scale + p * blo(u);
    acc1 = acc1 * scale + p * bhi(u);
    m = mx;
  }
  float inv = 1.f / denom;
  float2 b = ((const float2*)bias)[lane];
  ((float2*)(out + (size_t)node * 128))[lane] = make_float2(acc0 * inv + b.x, acc1 * inv + b.y);
}

extern "C" void kernel_launch(void* const* d_in, const int* in_sizes, int n_in,
                              void* d_out, int out_size, void* d_ws, size_t ws_size,
                              hipStream_t stream) {
  const float* x     = (const float*)d_in[0];
  const int*   ei    = (const int*)d_in[1];
  const float* W     = (const float*)d_in[2];
  const float* a_src = (const float*)d_in[3];
  const float* a_dst = (const float*)d_in[4];
  const float* bias  = (const float*)d_in[5];
  float* out = (float*)d_out;

  int n = in_sizes[0] / 128;   // IN = 128
  int e = in_sizes[1] / 2;
  int NB = (n + 127) >> 7;     // dst buckets of 128 nodes
  int nb8 = NB * 8;

  char* ws = (char*)d_ws;
  size_t ofs = 0;
  auto alloc = [&](size_t bytes) { void* p = ws + ofs; ofs = (ofs + bytes + 15) & ~(size_t)15; return p; };
  __bf16* h     = (__bf16*)alloc((size_t)n * 128 * sizeof(__bf16));   // 25.6 MB
  unsigned* h32 = (unsigned*)h;
  float* asrc   = (float*)alloc((size_t)n * 4 * sizeof(float));
  float* adst   = (float*)alloc((size_t)n * 4 * sizeof(float));
  int* off      = (int*)alloc((size_t)(n + 1) * sizeof(int));
  int* bgcnt    = (int*)alloc((size_t)nb8 * sizeof(int));
  int* boffbg   = (int*)alloc((size_t)(nb8 + 1) * sizeof(int));
  int* bcur     = (int*)alloc((size_t)nb8 * sizeof(int));
  int* adj      = (int*)alloc((size_t)e * sizeof(int));               // 6.4 MB
  unsigned* ebuf = (unsigned*)alloc((size_t)e * sizeof(unsigned));    // 6.4 MB
  __bf16* Wt    = (__bf16*)alloc((size_t)128 * 128 * sizeof(__bf16)); // 32 KB

  hipLaunchKernelGGL(k_init, dim3((n + 255) / 256), dim3(256), 0, stream, bgcnt, off, n, e, nb8);
  hipLaunchKernelGGL(k_wprep, dim3(64), dim3(256), 0, stream, W, Wt);
  hipLaunchKernelGGL(k_gemm, dim3((n + 64 * CPB - 1) / (64 * CPB)), dim3(256), 0, stream, x, Wt, h, n);
  hipLaunchKernelGGL(k_alpha, dim3((n * 64 + 255) / 256), dim3(256), 0, stream,
                     h32, a_src, a_dst, asrc, adst, n);
  hipLaunchKernelGGL(k_bcount, dim3(512), dim3(256), 0, stream, ei, bgcnt, e, NB);
  hipLaunchKernelGGL(k_bscan, dim3(1), dim3(256), 0, stream, bgcnt, boffbg, bcur, nb8, e);
  hipLaunchKernelGGL(k_bfill, dim3(512), dim3(256), 0, stream, ei, bcur, ebuf, e);
  hipLaunchKernelGGL(k_csr, dim3(NB), dim3(256), 0, stream, ebuf, boffbg, off, adj, n);
  hipLaunchKernelGGL(k_reduce, dim3((n * 64 + 255) / 256), dim3(256), 0, stream,
                     adj, off, asrc, adst, h32, bias, out, n);
}